// Round 1
// baseline (1022.070 us; speedup 1.0000x reference)
//
#include <hip/hip_runtime.h>
#include <stdint.h>

typedef unsigned int u32;
typedef unsigned long long u64;

#define NPTS 8192
#define NT   128   // 128x128 tiles of 64x64

// ws layout (bytes)
#define WS_HIST    0        // u32 hist[2][256]
#define WS_STATE   2048     // u32 prefix0, prefix1, base0, base1
#define WS_DC      2080     // float dc
#define WS_SQ      4096     // float sq[8192]
#define WS_ROWMAX  36864    // u32 rowmax_bits[8192]
#define WS_RHOD    69632    // double rho_d[8192]
#define WS_RHOF    135168   // float rho_f[8192]
#define WS_MINKEY  167936   // u64 minkey[8192]  (ends at 233472)

#define K_RANK 1342177ull   // floor(0.02f * fp32(N*N-1)) ; frac = 0.25

__device__ __forceinline__ u64 umin64(u64 a, u64 b) { return a < b ? a : b; }

// Computes the 64x64 distance tile (bi,bj); each of 256 threads owns a 4x4
// register tile. LDS staged k-major [64 k][68 pad] so the hot loop reads are
// two ds_read_b128 per k (A: 16-lane broadcast, B: 2-way = free).
__device__ __forceinline__ void compute_tile(
    const float* __restrict__ X, const float* __restrict__ sq,
    int bi, int bj, int tx, int ty, float (&dist)[4][4])
{
  __shared__ __align__(16) float As[64][68];
  __shared__ __align__(16) float Bs[64][68];
  const int tid = threadIdx.x;
  const float4* Xv = reinterpret_cast<const float4*>(X);
#pragma unroll
  for (int rep = 0; rep < 4; ++rep) {
    int idx = rep * 256 + tid;      // 0..1023
    int i   = idx >> 4;             // 0..63 row in strip
    int kq  = idx & 15;             // float4 index along k
    int k4  = kq << 2;
    float4 va = Xv[(bi * 64 + i) * 16 + kq];
    As[k4 + 0][i] = va.x; As[k4 + 1][i] = va.y; As[k4 + 2][i] = va.z; As[k4 + 3][i] = va.w;
    float4 vb = Xv[(bj * 64 + i) * 16 + kq];
    Bs[k4 + 0][i] = vb.x; Bs[k4 + 1][i] = vb.y; Bs[k4 + 2][i] = vb.z; Bs[k4 + 3][i] = vb.w;
  }
  __syncthreads();

  float acc[4][4] = {};
#pragma unroll 8
  for (int k = 0; k < 64; ++k) {     // sequential k chain: bit-identical across all passes
    float4 av = *reinterpret_cast<const float4*>(&As[k][ty * 4]);
    float4 bv = *reinterpret_cast<const float4*>(&Bs[k][tx * 4]);
    float a[4] = {av.x, av.y, av.z, av.w};
    float b[4] = {bv.x, bv.y, bv.z, bv.w};
#pragma unroll
    for (int r = 0; r < 4; ++r)
#pragma unroll
      for (int c = 0; c < 4; ++c)
        acc[r][c] = fmaf(a[r], b[c], acc[r][c]);
  }

  float sqa[4], sqb[4];
#pragma unroll
  for (int r = 0; r < 4; ++r) sqa[r] = sq[bi * 64 + ty * 4 + r];
#pragma unroll
  for (int c = 0; c < 4; ++c) sqb[c] = sq[bj * 64 + tx * 4 + c];
#pragma unroll
  for (int r = 0; r < 4; ++r)
#pragma unroll
    for (int c = 0; c < 4; ++c) {
      float d2 = (sqa[r] + sqb[c]) - 2.0f * acc[r][c];
      dist[r][c] = sqrtf(fmaxf(d2, 0.0f));
    }
}

__global__ __launch_bounds__(256) void k_init(u32* __restrict__ ws) {
  int t = blockIdx.x * 256 + threadIdx.x;     // 8192 threads
  if (t < 516) ws[t] = 0;                     // hists + sel-state
  ws[WS_ROWMAX / 4 + t] = 0;
  reinterpret_cast<double*>((char*)ws + WS_RHOD)[t] = 0.0;
  reinterpret_cast<u64*>((char*)ws + WS_MINKEY)[t] = ~0ull;
}

__global__ __launch_bounds__(256) void k_sq(const float* __restrict__ X, float* __restrict__ sq) {
  int i = blockIdx.x * 256 + threadIdx.x;
  const float4* row = reinterpret_cast<const float4*>(X + i * 64);
  float s = 0.f;
#pragma unroll
  for (int q = 0; q < 16; ++q) {
    float4 v = row[q];
    s = fmaf(v.x, v.x, s); s = fmaf(v.y, v.y, s);
    s = fmaf(v.z, v.z, s); s = fmaf(v.w, v.w, s);
  }
  sq[i] = s;   // identical fma chain to tile dot(i,i) -> diagonal d2 == 0 exactly
}

__global__ __launch_bounds__(256) void k_hist(
    const float* __restrict__ X, const float* __restrict__ sq,
    u32* __restrict__ ws, int shift, u32 mask, int do_rowmax)
{
  const int bi = blockIdx.y, bj = blockIdx.x;
  if (bj < bi) return;                       // upper triangle only
  const int tid = threadIdx.x;
  const int tx = tid & 15, ty = tid >> 4;
  __shared__ u32 h0[256], h1[256];
  h0[tid] = 0; h1[tid] = 0;                  // ordered by compute_tile's barrier
  float dist[4][4];
  compute_tile(X, sq, bi, bj, tx, ty, dist);

  const u32* st = ws + 512;
  const u32 p0 = st[0], p1 = st[1];
  const bool same = (p0 == p1);
  const int ig0 = bi * 64 + ty * 4, jg0 = bj * 64 + tx * 4;
#pragma unroll
  for (int r = 0; r < 4; ++r)
#pragma unroll
    for (int c = 0; c < 4; ++c) {
      int ig = ig0 + r, jg = jg0 + c;
      u32 w = (bi < bj) ? 2u : (ig < jg ? 2u : (ig == jg ? 1u : 0u));
      if (w) {
        u32 bits = __float_as_uint(dist[r][c]);
        if ((bits & mask) == p0) atomicAdd(&h0[(bits >> shift) & 255u], w);
        if (!same && (bits & mask) == p1) atomicAdd(&h1[(bits >> shift) & 255u], w);
      }
    }

  if (do_rowmax) {
    u32* rowmax = ws + WS_ROWMAX / 4;
    float rmA[4], rmB[4];
#pragma unroll
    for (int r = 0; r < 4; ++r)
      rmA[r] = fmaxf(fmaxf(dist[r][0], dist[r][1]), fmaxf(dist[r][2], dist[r][3]));
#pragma unroll
    for (int c = 0; c < 4; ++c)
      rmB[c] = fmaxf(fmaxf(dist[0][c], dist[1][c]), fmaxf(dist[2][c], dist[3][c]));
#pragma unroll
    for (int m = 1; m <= 8; m <<= 1)
#pragma unroll
      for (int r = 0; r < 4; ++r) rmA[r] = fmaxf(rmA[r], __shfl_xor(rmA[r], m));
    if ((tid & 15) == 0)
#pragma unroll
      for (int r = 0; r < 4; ++r) atomicMax(&rowmax[ig0 + r], __float_as_uint(rmA[r]));
#pragma unroll
    for (int m = 16; m <= 32; m <<= 1)
#pragma unroll
      for (int c = 0; c < 4; ++c) rmB[c] = fmaxf(rmB[c], __shfl_xor(rmB[c], m));
    if ((tid & 48) == 0)
#pragma unroll
      for (int c = 0; c < 4; ++c) atomicMax(&rowmax[jg0 + c], __float_as_uint(rmB[c]));
  }

  __syncthreads();
  if (h0[tid]) atomicAdd(&ws[tid], h0[tid]);
  if (!same && h1[tid]) atomicAdd(&ws[256 + tid], h1[tid]);
}

__global__ __launch_bounds__(256) void k_select(u32* __restrict__ ws, int shift, int final_pass) {
  if (threadIdx.x == 0) {
    u32* st = ws + 512;
    u32 p0 = st[0], p1 = st[1];
    u64 b0 = st[2], b1 = st[3];
    const u32* h0 = ws;
    const u32* h1 = ws + 256;
    bool same = (p0 == p1);
    u64 cum = b0;
    for (int b = 0; b < 256; ++b) {
      u32 c = h0[b];
      if (cum + c > K_RANK) { st[0] = p0 | ((u32)b << shift); st[2] = (u32)cum; break; }
      cum += c;
    }
    const u32* hs = same ? h0 : h1;
    cum = b1;
    for (int b = 0; b < 256; ++b) {
      u32 c = hs[b];
      if (cum + c > K_RANK + 1ull) { st[1] = p1 | ((u32)b << shift); st[3] = (u32)cum; break; }
      cum += c;
    }
    if (final_pass) {
      float v0 = __uint_as_float(st[0]);
      float v1 = __uint_as_float(st[1]);
      double dc = 0.75 * (double)v0 + 0.25 * (double)v1;  // fp32 rank 1342177.25
      *reinterpret_cast<float*>((char*)ws + WS_DC) = (float)dc;
    }
  }
  __syncthreads();
  ws[threadIdx.x] = 0;          // zero hists for next pass
  ws[256 + threadIdx.x] = 0;
}

__global__ __launch_bounds__(256) void k_rho(
    const float* __restrict__ X, const float* __restrict__ sq, u32* __restrict__ ws)
{
  const int bi = blockIdx.y, bj = blockIdx.x;
  if (bj < bi) return;
  const int tid = threadIdx.x;
  const int tx = tid & 15, ty = tid >> 4;
  float dist[4][4];
  compute_tile(X, sq, bi, bj, tx, ty, dist);
  const float dcf = *reinterpret_cast<const float*>((const char*)ws + WS_DC);
  const float inv = 1.0f / dcf;
  const int ig0 = bi * 64 + ty * 4, jg0 = bj * 64 + tx * 4;
  const bool diag = (bi == bj);
  float rA[4] = {}, rB[4] = {};
#pragma unroll
  for (int r = 0; r < 4; ++r)
#pragma unroll
    for (int c = 0; c < 4; ++c) {
      float q = dist[r][c] * inv;
      float t = __expf(-(q * q));
      if (!diag) { rA[r] += t; rB[c] += t; }
      else {
        int ig = ig0 + r, jg = jg0 + c;
        if (ig < jg) { rA[r] += t; rB[c] += t; }
        else if (ig == jg) rA[r] += t;
      }
    }
  double* rhod = reinterpret_cast<double*>((char*)ws + WS_RHOD);
#pragma unroll
  for (int m = 1; m <= 8; m <<= 1)
#pragma unroll
    for (int r = 0; r < 4; ++r) rA[r] += __shfl_xor(rA[r], m);
  if ((tid & 15) == 0)
#pragma unroll
    for (int r = 0; r < 4; ++r) atomicAdd(&rhod[ig0 + r], (double)rA[r]);
#pragma unroll
  for (int m = 16; m <= 32; m <<= 1)
#pragma unroll
    for (int c = 0; c < 4; ++c) rB[c] += __shfl_xor(rB[c], m);
  if ((tid & 48) == 0)
#pragma unroll
    for (int c = 0; c < 4; ++c) atomicAdd(&rhod[jg0 + c], (double)rB[c]);
}

__global__ __launch_bounds__(256) void k_cast(u32* __restrict__ ws) {
  int t = blockIdx.x * 256 + threadIdx.x;
  reinterpret_cast<float*>((char*)ws + WS_RHOF)[t] =
      (float)reinterpret_cast<const double*>((const char*)ws + WS_RHOD)[t];
}

__global__ __launch_bounds__(256) void k_delta(
    const float* __restrict__ X, const float* __restrict__ sq, u32* __restrict__ ws)
{
  const int bi = blockIdx.y, bj = blockIdx.x;
  if (bj < bi) return;
  const int tid = threadIdx.x;
  const int tx = tid & 15, ty = tid >> 4;
  float dist[4][4];
  compute_tile(X, sq, bi, bj, tx, ty, dist);
  const float* rhof = reinterpret_cast<const float*>((const char*)ws + WS_RHOF);
  const int ig0 = bi * 64 + ty * 4, jg0 = bj * 64 + tx * 4;
  float ri[4], rj[4];
#pragma unroll
  for (int r = 0; r < 4; ++r) ri[r] = rhof[ig0 + r];
#pragma unroll
  for (int c = 0; c < 4; ++c) rj[c] = rhof[jg0 + c];
  u64 bA[4] = {~0ull, ~0ull, ~0ull, ~0ull};
  u64 bB[4] = {~0ull, ~0ull, ~0ull, ~0ull};
  const bool offd = (bi < bj);
#pragma unroll
  for (int r = 0; r < 4; ++r)
#pragma unroll
    for (int c = 0; c < 4; ++c) {
      int ig = ig0 + r, jg = jg0 + c;
      if (offd || ig < jg) {
        u64 kb = ((u64)__float_as_uint(dist[r][c])) << 32;  // (bits,idx) key: min => (min dist, first idx)
        if (rj[c] > ri[r]) bA[r] = umin64(bA[r], kb | (u64)(u32)jg);
        if (ri[r] > rj[c]) bB[c] = umin64(bB[c], kb | (u64)(u32)ig);
      }
    }
  u64* mk = reinterpret_cast<u64*>((char*)ws + WS_MINKEY);
#pragma unroll
  for (int m = 1; m <= 8; m <<= 1)
#pragma unroll
    for (int r = 0; r < 4; ++r) bA[r] = umin64(bA[r], __shfl_xor(bA[r], m));
  if ((tid & 15) == 0)
#pragma unroll
    for (int r = 0; r < 4; ++r) atomicMin(&mk[ig0 + r], bA[r]);
#pragma unroll
  for (int m = 16; m <= 32; m <<= 1)
#pragma unroll
    for (int c = 0; c < 4; ++c) bB[c] = umin64(bB[c], __shfl_xor(bB[c], m));
  if ((tid & 48) == 0)
#pragma unroll
    for (int c = 0; c < 4; ++c) atomicMin(&mk[jg0 + c], bB[c]);
}

__global__ __launch_bounds__(1024) void k_labels(
    const u32* __restrict__ ws, const float* __restrict__ rtp,
    const float* __restrict__ dtp, int* __restrict__ out)
{
  __shared__ int   nhd_s[NPTS];   // 32 KB
  __shared__ short lab_s[NPTS];   // 16 KB
  __shared__ int   tsum[1024];    //  4 KB
  const int t = threadIdx.x;
  const float rt = rtp[0], dt = dtp[0];
  const u64* mk = reinterpret_cast<const u64*>((const char*)ws + WS_MINKEY);
  const u32* rowmax = ws + WS_ROWMAX / 4;
  const float* rhof = reinterpret_cast<const float*>((const char*)ws + WS_RHOF);
  int cnt = 0;
  short loc[8];
#pragma unroll
  for (int e = 0; e < 8; ++e) {
    int i = t * 8 + e;
    u64 key = mk[i];
    bool hh = (key != ~0ull);
    float delta = hh ? __uint_as_float((u32)(key >> 32)) : __uint_as_float(rowmax[i]);
    int nh = hh ? (int)(u32)(key & 0xffffffffull) : i;
    nhd_s[i] = nh;
    bool isc = (rhof[i] > rt) && (delta > dt);
    loc[e] = isc ? (short)cnt : (short)-1;
    cnt += isc ? 1 : 0;
  }
  tsum[t] = cnt;
  __syncthreads();
  if (t == 0) {                 // 1024-entry serial exclusive scan: negligible
    int run = 0;
    for (int x = 0; x < 1024; ++x) { int c = tsum[x]; tsum[x] = run; run += c; }
  }
  __syncthreads();
  int base = tsum[t];
#pragma unroll
  for (int e = 0; e < 8; ++e) {
    int i = t * 8 + e;
    lab_s[i] = (loc[e] >= 0) ? (short)(loc[e] + base) : (short)-1;
  }
  __syncthreads();
  // label = labels0[root of nhd chain] — order-independent equivalent of the scan
#pragma unroll
  for (int e = 0; e < 8; ++e) {
    int i = t * 8 + e;
    int cur = i;
    while (lab_s[cur] < 0 && nhd_s[cur] != cur) cur = nhd_s[cur];
    out[i] = (int)lab_s[cur];
  }
}

extern "C" void kernel_launch(void* const* d_in, const int* in_sizes, int n_in,
                              void* d_out, int out_size, void* d_ws, size_t ws_size,
                              hipStream_t stream)
{
  (void)in_sizes; (void)n_in; (void)out_size; (void)ws_size;
  const float* X  = (const float*)d_in[0];
  const float* rt = (const float*)d_in[1];
  const float* dt = (const float*)d_in[2];
  int* out = (int*)d_out;
  u32* ws = (u32*)d_ws;
  float* sq = (float*)((char*)d_ws + WS_SQ);

  k_init<<<32, 256, 0, stream>>>(ws);
  k_sq<<<32, 256, 0, stream>>>(X, sq);

  dim3 tri(NT, NT);
  const int shifts[4] = {24, 16, 8, 0};
  const u32 masks[4] = {0u, 0xFF000000u, 0xFFFF0000u, 0xFFFFFF00u};
  for (int p = 0; p < 4; ++p) {
    k_hist<<<tri, 256, 0, stream>>>(X, sq, ws, shifts[p], masks[p], p == 0 ? 1 : 0);
    k_select<<<1, 256, 0, stream>>>(ws, shifts[p], p == 3 ? 1 : 0);
  }
  k_rho<<<tri, 256, 0, stream>>>(X, sq, ws);
  k_cast<<<32, 256, 0, stream>>>(ws);
  k_delta<<<tri, 256, 0, stream>>>(X, sq, ws);
  k_labels<<<1, 1024, 0, stream>>>(ws, rt, dt, out);
}

// Round 2
// 737.424 us; speedup vs baseline: 1.3860x; 1.3860x over previous
//
#include <hip/hip_runtime.h>
#include <stdint.h>

typedef unsigned int u32;
typedef unsigned long long u64;

#define NPTS 8192
#define NB   64            // 64x64 grid of 128x128 tiles

// ws byte offsets
#define WS_HIST    0       // u32 h0[2048], h1[2048]  (16384 B)
#define WS_STATE   16384   // u32 p0,p1,b0,b1
#define WS_DC      16400   // float dc
#define WS_SQ      20480   // float sq[8192]
#define WS_ROWMAX  53248   // u32 rowmax d2-bits[8192]
#define WS_RHOD    86016   // double rho[8192]
#define WS_RHOF    151552  // float rho[8192]
#define WS_MINKEY  184320  // u64 minkey[8192] (ends 249856)

#define K_RANK 1342177ull  // floor(0.02f * fp32(N*N-1)); frac = 0.25 (fp32-exact, validated r1)

__device__ __forceinline__ u64 umin64(u64 a, u64 b) { return a < b ? a : b; }

// 128x128 d2 tile; 256 threads, 8x8 frags; k staged in 2 phases of 32.
// LDS layout k-major [32][132] with XOR swizzle col' = ((i>>2)^(k>>3))*4 + (i&3):
// staging writes = 2 lanes/bank (free), reads stay 16B-aligned b128.
__device__ __forceinline__ void tile128(
    const float* __restrict__ X, const float* __restrict__ sq,
    float (*As)[132], float (*Bs)[132],
    int bi, int bj, int tx, int ty, float (&d2)[8][8])
{
  const int tid = threadIdx.x;
  const float4* Xv = reinterpret_cast<const float4*>(X);
  float acc[8][8] = {};
  for (int ph = 0; ph < 2; ++ph) {
    if (ph) __syncthreads();          // protect LDS before overwrite
#pragma unroll
    for (int rep = 0; rep < 4; ++rep) {
      int idx = rep * 256 + tid;      // 0..1023
      int i   = idx >> 3;             // row 0..127
      int q   = idx & 7;              // local k-quad
      int col = (((i >> 2) ^ (q >> 1)) << 2) | (i & 3);
      float4 va = Xv[(bi * 128 + i) * 16 + ph * 8 + q];
      As[4*q+0][col] = va.x; As[4*q+1][col] = va.y; As[4*q+2][col] = va.z; As[4*q+3][col] = va.w;
      float4 vb = Xv[(bj * 128 + i) * 16 + ph * 8 + q];
      Bs[4*q+0][col] = vb.x; Bs[4*q+1][col] = vb.y; Bs[4*q+2][col] = vb.z; Bs[4*q+3][col] = vb.w;
    }
    __syncthreads();
#pragma unroll
    for (int c8 = 0; c8 < 4; ++c8) {  // s(k) = k>>3 = c8, constant per chunk
#pragma unroll
      for (int u = 0; u < 8; ++u) {
        int k = c8 * 8 + u;
        float4 a0 = *reinterpret_cast<const float4*>(&As[k][((2*ty+0) ^ c8) << 2]);
        float4 a1 = *reinterpret_cast<const float4*>(&As[k][((2*ty+1) ^ c8) << 2]);
        float4 b0 = *reinterpret_cast<const float4*>(&Bs[k][((2*tx+0) ^ c8) << 2]);
        float4 b1 = *reinterpret_cast<const float4*>(&Bs[k][((2*tx+1) ^ c8) << 2]);
        float a[8] = {a0.x,a0.y,a0.z,a0.w,a1.x,a1.y,a1.z,a1.w};
        float b[8] = {b0.x,b0.y,b0.z,b0.w,b1.x,b1.y,b1.z,b1.w};
#pragma unroll
        for (int r = 0; r < 8; ++r)
#pragma unroll
          for (int c = 0; c < 8; ++c)
            acc[r][c] = fmaf(a[r], b[c], acc[r][c]);
      }
    }
  }
  float sqa[8], sqb[8];
#pragma unroll
  for (int r = 0; r < 8; ++r) sqa[r] = sq[bi * 128 + ty * 8 + r];
#pragma unroll
  for (int c = 0; c < 8; ++c) sqb[c] = sq[bj * 128 + tx * 8 + c];
#pragma unroll
  for (int r = 0; r < 8; ++r)
#pragma unroll
    for (int c = 0; c < 8; ++c)
      d2[r][c] = fmaxf((sqa[r] + sqb[c]) - 2.0f * acc[r][c], 0.0f);
}

__global__ __launch_bounds__(256) void k_init(u32* __restrict__ ws) {
  int t = blockIdx.x * 256 + threadIdx.x;     // 8192 threads
  if (t < 4100) ws[t] = 0;                    // hists + state
  ws[WS_ROWMAX / 4 + t] = 0;
  reinterpret_cast<double*>((char*)ws + WS_RHOD)[t] = 0.0;
  reinterpret_cast<u64*>((char*)ws + WS_MINKEY)[t] = ~0ull;
}

__global__ __launch_bounds__(256) void k_sq(const float* __restrict__ X, float* __restrict__ sq) {
  int i = blockIdx.x * 256 + threadIdx.x;
  const float4* row = reinterpret_cast<const float4*>(X + i * 64);
  float s = 0.f;
#pragma unroll
  for (int q = 0; q < 16; ++q) {
    float4 v = row[q];
    s = fmaf(v.x, v.x, s); s = fmaf(v.y, v.y, s);
    s = fmaf(v.z, v.z, s); s = fmaf(v.w, v.w, s);
  }
  sq[i] = s;   // identical fma chain to tile dot(i,i) -> diagonal d2 == 0 exactly
}

// radix-select pass over d2 bits; 11-bit digit at `shift`, prefix-filtered by `prefmask`.
// LDS histogram (x4 replicas) reuses the tile buffers after compute.
__global__ __launch_bounds__(256, 4) void k_hist(
    const float* __restrict__ X, const float* __restrict__ sq,
    u32* __restrict__ ws, int shift, u32 prefmask, int do_rowmax)
{
  __shared__ __align__(16) char smem[40960];
  float (*As)[132] = reinterpret_cast<float(*)[132]>(smem);
  float (*Bs)[132] = reinterpret_cast<float(*)[132]>(smem + 16896);
  u32* h0 = reinterpret_cast<u32*>(smem);          // 2048*4 replicas = 32 KB
  u32* h1 = reinterpret_cast<u32*>(smem + 32768);  // 2048        = 8 KB

  const int bi = blockIdx.y, bj = blockIdx.x;
  if (bj < bi) return;
  const int tid = threadIdx.x;
  const int tx = tid & 15, ty = tid >> 4;
  float d2[8][8];
  tile128(X, sq, As, Bs, bi, bj, tx, ty, d2);

  const int ig0 = bi * 128 + ty * 8, jg0 = bj * 128 + tx * 8;

  if (do_rowmax) {   // registers + shuffles + global atomics only (d2 bits: uint order == float order)
    u32* rowmax = ws + WS_ROWMAX / 4;
    u32 rmA[8], rmB[8];
#pragma unroll
    for (int r = 0; r < 8; ++r) {
      u32 m = 0;
#pragma unroll
      for (int c = 0; c < 8; ++c) m = max(m, __float_as_uint(d2[r][c]));
      rmA[r] = m;
    }
#pragma unroll
    for (int c = 0; c < 8; ++c) {
      u32 m = 0;
#pragma unroll
      for (int r = 0; r < 8; ++r) m = max(m, __float_as_uint(d2[r][c]));
      rmB[c] = m;
    }
#pragma unroll
    for (int m = 1; m <= 8; m <<= 1)
#pragma unroll
      for (int r = 0; r < 8; ++r) rmA[r] = max(rmA[r], (u32)__shfl_xor((int)rmA[r], m));
    if ((tid & 15) == 0)
#pragma unroll
      for (int r = 0; r < 8; ++r) atomicMax(&rowmax[ig0 + r], rmA[r]);
#pragma unroll
    for (int m = 16; m <= 32; m <<= 1)
#pragma unroll
      for (int c = 0; c < 8; ++c) rmB[c] = max(rmB[c], (u32)__shfl_xor((int)rmB[c], m));
    if ((tid & 48) == 0)
#pragma unroll
      for (int c = 0; c < 8; ++c) atomicMax(&rowmax[jg0 + c], rmB[c]);
  }

  const u32* st = ws + 4096;
  const u32 p0 = st[0], p1 = st[1];
  const bool same = (p0 == p1);

  __syncthreads();                                  // done reading tile LDS
  for (int i = tid; i < 10240; i += 256) reinterpret_cast<u32*>(smem)[i] = 0;
  __syncthreads();

  const bool offd = (bi < bj);
  const int rep4 = tid & 3;
#pragma unroll
  for (int r = 0; r < 8; ++r)
#pragma unroll
    for (int c = 0; c < 8; ++c) {
      int ig = ig0 + r, jg = jg0 + c;
      u32 w = offd ? 2u : (ig < jg ? 2u : (ig == jg ? 1u : 0u));
      if (w) {
        u32 bits = __float_as_uint(d2[r][c]);
        if ((bits & prefmask) == p0) atomicAdd(&h0[(((bits >> shift) & 2047u) << 2) | rep4], w);
        if (!same && (bits & prefmask) == p1) atomicAdd(&h1[(bits >> shift) & 2047u], w);
      }
    }

  __syncthreads();
  for (int b = tid; b < 2048; b += 256) {
    u32 s = h0[4*b] + h0[4*b+1] + h0[4*b+2] + h0[4*b+3];
    if (s) atomicAdd(&ws[b], s);
    if (!same) { u32 s1 = h1[b]; if (s1) atomicAdd(&ws[2048 + b], s1); }
  }
}

__global__ __launch_bounds__(256) void k_select(u32* __restrict__ ws, int shift, int final_pass) {
  __shared__ u32 cs0[256], cs1[256];
  const int t = threadIdx.x;
  const u32* g0 = ws;
  const u32* g1 = ws + 2048;
  u32* st = ws + 4096;
  u32 s0 = 0, s1 = 0;
#pragma unroll
  for (int e = 0; e < 8; ++e) { s0 += g0[t*8+e]; s1 += g1[t*8+e]; }
  cs0[t] = s0; cs1[t] = s1;
  __syncthreads();
  if (t == 0) {
    u32 p0 = st[0], p1 = st[1];
    bool same = (p0 == p1);
    u64 cum = st[2];
    int ch = 0; while (ch < 256 && cum + cs0[ch] <= K_RANK) { cum += cs0[ch]; ++ch; }
    int b = ch * 8; while (b < 2047 && cum + g0[b] <= K_RANK) { cum += g0[b]; ++b; }
    st[0] = p0 | ((u32)b << shift); st[2] = (u32)cum;
    const u32* g = same ? g0 : g1;
    const u32* cs = same ? cs0 : cs1;
    cum = st[3];
    ch = 0; while (ch < 256 && cum + cs[ch] <= K_RANK + 1ull) { cum += cs[ch]; ++ch; }
    b = ch * 8; while (b < 2047 && cum + g[b] <= K_RANK + 1ull) { cum += g[b]; ++b; }
    st[1] = p1 | ((u32)b << shift); st[3] = (u32)cum;
    if (final_pass) {
      float w0 = sqrtf(__uint_as_float(st[0]));   // exact dist order stats
      float w1 = sqrtf(__uint_as_float(st[1]));
      double dc = 0.75 * (double)w0 + 0.25 * (double)w1;
      *reinterpret_cast<float*>((char*)ws + WS_DC) = (float)dc;
    }
  }
  __syncthreads();
  for (int i = t; i < 4096; i += 256) ws[i] = 0;   // zero global hists for next pass
}

__global__ __launch_bounds__(256, 4) void k_rho(
    const float* __restrict__ X, const float* __restrict__ sq, u32* __restrict__ ws)
{
  __shared__ __align__(16) char smem[33792];
  float (*As)[132] = reinterpret_cast<float(*)[132]>(smem);
  float (*Bs)[132] = reinterpret_cast<float(*)[132]>(smem + 16896);
  const int bi = blockIdx.y, bj = blockIdx.x;
  if (bj < bi) return;
  const int tid = threadIdx.x;
  const int tx = tid & 15, ty = tid >> 4;
  float d2[8][8];
  tile128(X, sq, As, Bs, bi, bj, tx, ty, d2);
  const float dcf = *reinterpret_cast<const float*>((const char*)ws + WS_DC);
  const float inv2 = 1.0f / (dcf * dcf);
  const int ig0 = bi * 128 + ty * 8, jg0 = bj * 128 + tx * 8;
  const bool diag = (bi == bj);
  float rA[8] = {}, rB[8] = {};
#pragma unroll
  for (int r = 0; r < 8; ++r)
#pragma unroll
    for (int c = 0; c < 8; ++c) {
      float t = __expf(-(d2[r][c] * inv2));
      if (!diag) { rA[r] += t; rB[c] += t; }
      else {
        int ig = ig0 + r, jg = jg0 + c;
        if (ig < jg) { rA[r] += t; rB[c] += t; }
        else if (ig == jg) rA[r] += t;
      }
    }
  double* rhod = reinterpret_cast<double*>((char*)ws + WS_RHOD);
#pragma unroll
  for (int m = 1; m <= 8; m <<= 1)
#pragma unroll
    for (int r = 0; r < 8; ++r) rA[r] += __shfl_xor(rA[r], m);
  if ((tid & 15) == 0)
#pragma unroll
    for (int r = 0; r < 8; ++r) atomicAdd(&rhod[ig0 + r], (double)rA[r]);
#pragma unroll
  for (int m = 16; m <= 32; m <<= 1)
#pragma unroll
    for (int c = 0; c < 8; ++c) rB[c] += __shfl_xor(rB[c], m);
  if ((tid & 48) == 0)
#pragma unroll
    for (int c = 0; c < 8; ++c) atomicAdd(&rhod[jg0 + c], (double)rB[c]);
}

__global__ __launch_bounds__(256) void k_cast(u32* __restrict__ ws) {
  int t = blockIdx.x * 256 + threadIdx.x;
  reinterpret_cast<float*>((char*)ws + WS_RHOF)[t] =
      (float)reinterpret_cast<const double*>((const char*)ws + WS_RHOD)[t];
}

__global__ __launch_bounds__(256, 4) void k_delta(
    const float* __restrict__ X, const float* __restrict__ sq, u32* __restrict__ ws)
{
  __shared__ __align__(16) char smem[33792];
  float (*As)[132] = reinterpret_cast<float(*)[132]>(smem);
  float (*Bs)[132] = reinterpret_cast<float(*)[132]>(smem + 16896);
  const int bi = blockIdx.y, bj = blockIdx.x;
  if (bj < bi) return;
  const int tid = threadIdx.x;
  const int tx = tid & 15, ty = tid >> 4;
  float d2[8][8];
  tile128(X, sq, As, Bs, bi, bj, tx, ty, d2);
  const float* rhof = reinterpret_cast<const float*>((const char*)ws + WS_RHOF);
  const int ig0 = bi * 128 + ty * 8, jg0 = bj * 128 + tx * 8;
  float ri[8], rj[8];
#pragma unroll
  for (int r = 0; r < 8; ++r) ri[r] = rhof[ig0 + r];
#pragma unroll
  for (int c = 0; c < 8; ++c) rj[c] = rhof[jg0 + c];
  u64 bA[8], bB[8];
#pragma unroll
  for (int r = 0; r < 8; ++r) { bA[r] = ~0ull; bB[r] = ~0ull; }
  const bool offd = (bi < bj);
#pragma unroll
  for (int r = 0; r < 8; ++r)
#pragma unroll
    for (int c = 0; c < 8; ++c) {
      int ig = ig0 + r, jg = jg0 + c;
      if (offd || ig < jg) {
        // sqrt here (not d2): reproduces reference argmin tie semantics exactly
        u64 kb = ((u64)__float_as_uint(sqrtf(d2[r][c]))) << 32;
        if (rj[c] > ri[r]) bA[r] = umin64(bA[r], kb | (u64)(u32)jg);
        if (ri[r] > rj[c]) bB[c] = umin64(bB[c], kb | (u64)(u32)ig);
      }
    }
  u64* mk = reinterpret_cast<u64*>((char*)ws + WS_MINKEY);
#pragma unroll
  for (int m = 1; m <= 8; m <<= 1)
#pragma unroll
    for (int r = 0; r < 8; ++r) bA[r] = umin64(bA[r], __shfl_xor(bA[r], m));
  if ((tid & 15) == 0)
#pragma unroll
    for (int r = 0; r < 8; ++r) atomicMin(&mk[ig0 + r], bA[r]);
#pragma unroll
  for (int m = 16; m <= 32; m <<= 1)
#pragma unroll
    for (int c = 0; c < 8; ++c) bB[c] = umin64(bB[c], __shfl_xor(bB[c], m));
  if ((tid & 48) == 0)
#pragma unroll
    for (int c = 0; c < 8; ++c) atomicMin(&mk[jg0 + c], bB[c]);
}

__global__ __launch_bounds__(1024) void k_labels(
    const u32* __restrict__ ws, const float* __restrict__ rtp,
    const float* __restrict__ dtp, int* __restrict__ out)
{
  __shared__ int   nhd_s[NPTS];   // 32 KB
  __shared__ short lab_s[NPTS];   // 16 KB
  __shared__ int   tsum[1024];    //  4 KB
  const int t = threadIdx.x;
  const float rt = rtp[0], dt = dtp[0];
  const u64* mk = reinterpret_cast<const u64*>((const char*)ws + WS_MINKEY);
  const u32* rowmax = ws + WS_ROWMAX / 4;
  const float* rhof = reinterpret_cast<const float*>((const char*)ws + WS_RHOF);
  int cnt = 0;
  short loc[8];
#pragma unroll
  for (int e = 0; e < 8; ++e) {
    int i = t * 8 + e;
    u64 key = mk[i];
    bool hh = (key != ~0ull);
    float delta = hh ? __uint_as_float((u32)(key >> 32))      // already sqrt'd in k_delta
                     : sqrtf(__uint_as_float(rowmax[i]));     // rowmax holds d2 bits
    int nh = hh ? (int)(u32)(key & 0xffffffffull) : i;
    nhd_s[i] = nh;
    bool isc = (rhof[i] > rt) && (delta > dt);
    loc[e] = isc ? (short)cnt : (short)-1;
    cnt += isc ? 1 : 0;
  }
  tsum[t] = cnt;
  __syncthreads();
  if (t == 0) {
    int run = 0;
    for (int x = 0; x < 1024; ++x) { int c = tsum[x]; tsum[x] = run; run += c; }
  }
  __syncthreads();
  int base = tsum[t];
#pragma unroll
  for (int e = 0; e < 8; ++e) {
    int i = t * 8 + e;
    lab_s[i] = (loc[e] >= 0) ? (short)(loc[e] + base) : (short)-1;
  }
  __syncthreads();
#pragma unroll
  for (int e = 0; e < 8; ++e) {
    int i = t * 8 + e;
    int cur = i;
    while (lab_s[cur] < 0 && nhd_s[cur] != cur) cur = nhd_s[cur];
    out[i] = (int)lab_s[cur];
  }
}

extern "C" void kernel_launch(void* const* d_in, const int* in_sizes, int n_in,
                              void* d_out, int out_size, void* d_ws, size_t ws_size,
                              hipStream_t stream)
{
  (void)in_sizes; (void)n_in; (void)out_size; (void)ws_size;
  const float* X  = (const float*)d_in[0];
  const float* rt = (const float*)d_in[1];
  const float* dt = (const float*)d_in[2];
  int* out = (int*)d_out;
  u32* ws = (u32*)d_ws;
  float* sq = (float*)((char*)d_ws + WS_SQ);

  k_init<<<32, 256, 0, stream>>>(ws);
  k_sq<<<32, 256, 0, stream>>>(X, sq);

  dim3 tri(NB, NB);
  // 3 radix passes on d2 bits: 11 + 11 + 10
  k_hist<<<tri, 256, 0, stream>>>(X, sq, ws, 21, 0u,          1);
  k_select<<<1, 256, 0, stream>>>(ws, 21, 0);
  k_hist<<<tri, 256, 0, stream>>>(X, sq, ws, 10, 0xFFE00000u, 0);
  k_select<<<1, 256, 0, stream>>>(ws, 10, 0);
  k_hist<<<tri, 256, 0, stream>>>(X, sq, ws,  0, 0xFFFFFC00u, 0);
  k_select<<<1, 256, 0, stream>>>(ws,  0, 1);

  k_rho<<<tri, 256, 0, stream>>>(X, sq, ws);
  k_cast<<<32, 256, 0, stream>>>(ws);
  k_delta<<<tri, 256, 0, stream>>>(X, sq, ws);
  k_labels<<<1, 1024, 0, stream>>>(ws, rt, dt, out);
}